// Round 16
// baseline (101.522 us; speedup 1.0000x reference)
//
#include <hip/hip_runtime.h>
#include <hip/hip_cooperative_groups.h>
#include <stdint.h>

// RPN RoI proposal -- R16: cooperative mega-kernel sized for WORST-CASE
// runtime occupancy (512 blocks, LDS union 31.3KB, launch_bounds(256,2) ->
// 2 blocks/CU under both 64KB and 160KB LDS assumptions), plus a
// query-gated fallback to the equivalent 4-kernel pipeline (shared
// __device__ phase functions; R14-proven logic). R15's coop launch was
// silently rejected (all-zero output): 1024 blocks x 37.4KB exceeded the
// runtime's co-residency budget.
//  P1 (B*8 blocks): threshold gather (bin>=CONS) -> bin-grouped per-slice
//     segments + per-slice 64-bin hist. key = flip(f32)<<32 | bin<<20 |
//     (0xFFFFF-idx): u64 desc == lax.top_k order (incl. tie-break).
//  P2 (B blocks): scanned hist tables -> arithmetic scatter dests; one-pass
//     scatter; zero-barrier per-wave segment sorts -> g_sorted. Exact
//     hist-2048 fallback in-branch (never taken).
//  P3 (B*8 blocks): decode 512 ranks into LDS; 64 rows x 16 words ->
//     g_supmat; each block s emits diag col-words for chunk q=s; s==0
//     persists g_boxes[0..512).
//  P4 (B blocks, 1 wave): chunked greedy sweep (ffs+ballot resolve; masked
//     pipelined propagation); early-exit at 300; exact fallback decodes to
//     global scratch (never taken); write clipped [300,4] zero-padded.

#define PRE 2000
#define POST 300
#define TILE 512
#define IOU_THR 0.7f
#define EPSV 1e-8f
#define SORTN 2048
#define NBINS 2048
#define DESTCAP 3584
#define CANDCAP 512
#define CONS 1984
#define SL 8
#define KBUF 1536

typedef unsigned long long u64;
namespace cg = cooperative_groups;

__device__ __forceinline__ uint32_t flip_f32(uint32_t b) {
    return b ^ ((uint32_t)((int32_t)b >> 31) | 0x80000000u);
}

__device__ __forceinline__ int bin_of(float s) {
    int bn = (int)(s * 2048.0f);
    return min(max(bn, 0), NBINS - 1);
}

__device__ __forceinline__ u64 make_key(float s, int idx, int bn) {
    uint32_t ub = flip_f32(__float_as_uint(s));
    return ((u64)ub << 32) | ((uint32_t)bn << 20) |
           (uint32_t)(0xFFFFF - idx);
}

__device__ __forceinline__ bool iou_gt(const float4& bi, float ai,
                                       const float4& bj, float aj) {
    float yy1 = fmaxf(bi.x, bj.x);
    float xx1 = fmaxf(bi.y, bj.y);
    float yy2 = fminf(bi.z, bj.z);
    float xx2 = fminf(bi.w, bj.w);
    float inter = fmaxf(yy2 - yy1, 0.f) * fmaxf(xx2 - xx1, 0.f);
    float iou = inter / (ai + aj - inter + EPSV);
    return iou > IOU_THR;
}

__device__ __forceinline__ float area_of(const float4& bx) {
    return fmaxf(bx.z - bx.x, 0.f) * fmaxf(bx.w - bx.y, 0.f);
}

// decode one key -> box (identical expression everywhere -> bit-exact)
__device__ __forceinline__ float4 decode_key(u64 key, const float4* dl,
                                             const float4* anchors, int N) {
    uint32_t idx = 0xFFFFFu - (uint32_t)(key & 0xFFFFFull);
    if (idx >= (uint32_t)N) return make_float4(0.f, 0.f, 0.f, 0.f);
    float4 d  = dl[idx];
    float4 an = anchors[idx];
    float ah  = an.z - an.x;
    float aw  = an.w - an.y;
    float acy = an.x + 0.5f * ah;
    float acx = an.y + 0.5f * aw;
    float h   = expf(d.z) * ah;
    float w   = expf(d.w) * aw;
    float cy  = d.x * ah + acy;
    float cx  = d.y * aw + acx;
    float y1  = cy - 0.5f * h;
    float x1  = cx - 0.5f * w;
    return make_float4(y1, x1, y1 + h, x1 + w);
}

__device__ __forceinline__ u64 cs_keep(u64 v, u64 pv, int i, int j, int k) {
    bool lower   = ((i & j) == 0);
    bool desc    = ((i & k) == 0);
    bool keepmax = (desc == lower);
    u64 mx = v > pv ? v : pv;
    u64 mn = v > pv ? pv : v;
    return keepmax ? mx : mn;
}

struct P1L {
    u64 keybuf[KBUF];
    u64 binbuf[KBUF];
    uint32_t hist64[64];
    int base64[64];
    uint32_t cur64[64];
    int kcnt;
};
struct P2L {
    u64 dest[DESTCAP];           // keys; fallback aliases sub-ranges
    int off[SL][64];             // scatter destination offsets
    int tot64[64];
    int segbase64[64];
    int flag, total, bsel, tprime, cnt, nc;
    uint32_t pivot;
};
struct P3L { float4 box[TILE]; };
struct P4L {
    uint32_t kept[POST];
    u64 keepbits[TILE / 64];
    uint32_t fmask[(PRE - TILE + 31) / 32];
};
union MegaLDS { P1L p1; P2L p2; P3L p3; P4L p4; };   // 31.3 KB

// ===================== P1: gather + per-slice binning ======================
__device__ void phase1(MegaLDS& u, int blk, int tid,
                       const float4* __restrict__ score4,
                       u64* __restrict__ g_pairs, int* __restrict__ g_scnt,
                       uint32_t* __restrict__ g_shist, int N)
{
    const int b = blk / SL;
    const int s = blk % SL;
    const int lane = tid & 63;
    const int F4PB = N >> 2;
    const int F4PS = (F4PB + SL - 1) / SL;

    if (tid < 64) { u.p1.hist64[tid] = 0u; u.p1.cur64[tid] = 0u; }
    if (tid == 0) u.p1.kcnt = 0;
    __syncthreads();

    const float4* src = score4 + (size_t)b * F4PB;
    const int n0 = s * F4PS, n1 = min(n0 + F4PS, F4PB);
    for (int n = n0 + tid; n < n1; n += 256) {
        float4 v = src[n];
        float sv[4] = {v.x, v.y, v.z, v.w};
#pragma unroll
        for (int c = 0; c < 4; ++c) {
            int bn = bin_of(sv[c]);
            if (bn >= CONS) {
                int q = atomicAdd(&u.p1.kcnt, 1);
                if (q < KBUF) u.p1.keybuf[q] = make_key(sv[c], 4 * n + c, bn);
            }
        }
    }
    __syncthreads();

    const int raw = u.p1.kcnt;
    const int lc  = min(raw, KBUF);

    for (int i = tid; i < lc; i += 256) {
        int b64 = (int)((u.p1.keybuf[i] >> 20) & 0xFFFu) - CONS;
        atomicAdd(&u.p1.hist64[b64], 1u);
    }
    __syncthreads();

    if (tid < 64) {
        int h = (int)u.p1.hist64[lane];
        int ssum = h;
#pragma unroll
        for (int off = 1; off < 64; off <<= 1) {
            int t = __shfl_down(ssum, off, 64);
            if (lane + off < 64) ssum += t;
        }
        u.p1.base64[lane] = ssum - h;    // keys in bins > lane (desc order)
    }
    __syncthreads();

    for (int i = tid; i < lc; i += 256) {
        u64 key = u.p1.keybuf[i];
        int b64 = (int)((key >> 20) & 0xFFFu) - CONS;
        int p = (int)atomicAdd(&u.p1.cur64[b64], 1u);
        u.p1.binbuf[u.p1.base64[b64] + p] = key;
    }
    __syncthreads();

    if (tid == 0) g_scnt[b * SL + s] = raw;
    if (tid < 64) g_shist[((size_t)b * SL + s) * 64 + tid] = u.p1.hist64[tid];
    u64* gp = g_pairs + ((size_t)b * SL + s) * KBUF;
    for (int i = tid; i < lc; i += 256) gp[i] = u.p1.binbuf[i];
}

// ===================== P2: scatter + segmented sort ========================
__device__ void phase2(MegaLDS& u, int b, int tid,
                       const float4* __restrict__ score4,
                       const u64* __restrict__ g_pairs,
                       const int* __restrict__ g_scnt,
                       const uint32_t* __restrict__ g_shist,
                       u64* __restrict__ g_sorted, int N)
{
    const int lane = tid & 63;
    const int wv4  = tid >> 6;
    const int F4PB = N >> 2;

    uint32_t* sh = (uint32_t*)u.p2.dest;     // shist staging alias (2KB)
    for (int i = tid; i < SL * 64; i += 256)
        sh[i] = g_shist[(size_t)b * SL * 64 + i];
    if (tid == 0) {
        int f = 0;
        for (int s = 0; s < SL; ++s)
            if (g_scnt[b * SL + s] > KBUF) f = 1;
        u.p2.flag = f;
    }
    __syncthreads();

    if (tid < 64) {                          // wave 0: totals + suffix scan
        int acc = 0;
#pragma unroll
        for (int s = 0; s < SL; ++s) acc += (int)sh[s * 64 + tid];
        u.p2.tot64[tid] = acc;
        if (acc > 128) u.p2.flag = 1;
        int ssum = acc;
#pragma unroll
        for (int off = 1; off < 64; off <<= 1) {
            int t = __shfl_down(ssum, off, 64);
            if (lane + off < 64) ssum += t;
        }
        u.p2.segbase64[tid] = ssum - acc;
        if (tid == 0) u.p2.total = ssum;
    }
    __syncthreads();
    const int total = u.p2.total;
    if (tid == 0 && (total < PRE || total > DESTCAP)) u.p2.flag = 1;
    // off[s][b64] = segbase + keys-of-bin-in-earlier-slices - in-slice-srcb
    for (int e = tid; e < SL * 64; e += 256) {
        int s = e >> 6, b64 = e & 63;
        int pre = 0;
        for (int s2 = 0; s2 < s; ++s2) pre += (int)sh[s2 * 64 + b64];
        int srcb = 0;
        for (int b2 = b64 + 1; b2 < 64; ++b2) srcb += (int)sh[s * 64 + b2];
        u.p2.off[s][b64] = u.p2.segbase64[b64] + pre - srcb;
    }
    __syncthreads();
    const bool flag = (u.p2.flag != 0);

    if (!flag) {
        // one-pass scatter; wave wv4 handles slices 2*wv4, 2*wv4+1
#pragma unroll
        for (int si = 0; si < 2; ++si) {
            int s = wv4 * 2 + si;
            const int cs = min(g_scnt[b * SL + s], KBUF);
            const u64* gp = g_pairs + ((size_t)b * SL + s) * KBUF;
            for (int i = lane; i < cs; i += 64) {
                u64 key = gp[i];
                int b64 = (int)((key >> 20) & 0xFFFu) - CONS;
                u.p2.dest[u.p2.off[s][b64] + i] = key;
            }
        }
        for (int q = total + tid; q < SORTN; q += 256) u.p2.dest[q] = 0ull;
        __syncthreads();
        // per-wave segment sorts (no barriers inside)
        for (int sgi = wv4; sgi < 64; sgi += 4) {
            int n = u.p2.tot64[sgi];
            if (n <= 0) continue;
            int base = u.p2.segbase64[sgi];
            if (n <= 64) {
                u64 e = (lane < n) ? u.p2.dest[base + lane] : 0ull;
#pragma unroll
                for (int k = 2; k <= 64; k <<= 1)
                    for (int j = k >> 1; j > 0; j >>= 1)
                        e = cs_keep(e, __shfl_xor(e, j, 64), lane, j, k);
                if (lane < n) u.p2.dest[base + lane] = e;
            } else {                         // 65..128
                u64 e0 = (lane < n) ? u.p2.dest[base + lane] : 0ull;
                u64 e1 = (lane + 64 < n) ? u.p2.dest[base + lane + 64] : 0ull;
#pragma unroll
                for (int k = 2; k <= 128; k <<= 1) {
                    for (int j = k >> 1; j > 0; j >>= 1) {
                        if (j == 64) {
                            u64 a = e0, c = e1;
                            e0 = cs_keep(a, c, lane, 64, k);
                            e1 = cs_keep(c, a, lane + 64, 64, k);
                        } else {
                            e0 = cs_keep(e0, __shfl_xor(e0, j, 64), lane, j, k);
                            e1 = cs_keep(e1, __shfl_xor(e1, j, 64), lane + 64, j, k);
                        }
                    }
                }
                if (lane < n) u.p2.dest[base + lane] = e0;
                if (lane + 64 < n) u.p2.dest[base + lane + 64] = e1;
            }
        }
        __syncthreads();
        for (int r = tid; r < SORTN; r += 256)
            g_sorted[(size_t)b * SORTN + r] = u.p2.dest[r];
    } else {
        // ---- exact fallback (never taken): hist-2048 top-2000 ----
        // aliases: keys dest[0..2048), hist2048 dest[2048..3072),
        //          cand dest[3072..3584)
        uint32_t* hist2048 = (uint32_t*)&u.p2.dest[2048];
        u64*      cand     = &u.p2.dest[3072];
        for (int i = tid; i < NBINS; i += 256) hist2048[i] = 0u;
        if (tid == 0) { u.p2.cnt = 0; u.p2.nc = 0; }
        __syncthreads();
        const float4* src = score4 + (size_t)b * F4PB;
        for (int n = tid; n < F4PB; n += 256) {
            float4 v = src[n];
            atomicAdd(&hist2048[bin_of(v.x)], 1u);
            atomicAdd(&hist2048[bin_of(v.y)], 1u);
            atomicAdd(&hist2048[bin_of(v.z)], 1u);
            atomicAdd(&hist2048[bin_of(v.w)], 1u);
        }
        __syncthreads();
        if (tid < 64) {                      // wave 0: chunked suffix scan
            int carry = 0;
            for (int c = 31; c >= 0; --c) {
                int h = (int)hist2048[c * 64 + lane];
                int s = h;
#pragma unroll
                for (int off = 1; off < 64; off <<= 1) {
                    int t = __shfl_down(s, off, 64);
                    if (lane + off < 64) s += t;
                }
                int S = s + carry;
                int Snext = S - h;
                if (S >= PRE && Snext < PRE) {
                    u.p2.bsel   = c * 64 + lane;
                    u.p2.tprime = PRE - Snext;
                }
                carry += __shfl(s, 0, 64);
            }
        }
        __syncthreads();
        const int bsel   = u.p2.bsel;
        const int tprime = u.p2.tprime;
        for (int n = tid; n < F4PB; n += 256) {
            float4 v = src[n];
            float sv[4] = {v.x, v.y, v.z, v.w};
#pragma unroll
            for (int c = 0; c < 4; ++c) {
                int bn = bin_of(sv[c]);
                if (bn >= bsel) {
                    u64 key = make_key(sv[c], 4 * n + c, bn);
                    if (bn > bsel) {
                        int q = atomicAdd(&u.p2.cnt, 1);
                        if (q < 2048) u.p2.dest[q] = key;
                    } else {
                        int t = atomicAdd(&u.p2.nc, 1);
                        if (t < CANDCAP) cand[t] = key;
                    }
                }
            }
        }
        __syncthreads();
        const int nc = min(u.p2.nc, CANDCAP);
        for (int i = tid; i < nc; i += 256) {
            uint32_t vi = (uint32_t)(cand[i] >> 32);
            int g = 0, e = 0;
            for (int j = 0; j < nc; ++j) {
                uint32_t vj = (uint32_t)(cand[j] >> 32);
                g += (vj > vi);
                e += (vj == vi);
            }
            if (g < tprime && g + e >= tprime) u.p2.pivot = vi;
        }
        __syncthreads();
        const uint32_t pivot = u.p2.pivot;
        for (int i = tid; i < nc; i += 256) {
            uint32_t vi = (uint32_t)(cand[i] >> 32);
            if (vi >= pivot) {
                int q = atomicAdd(&u.p2.cnt, 1);
                if (q < 2048) u.p2.dest[q] = cand[i];
            }
        }
        __syncthreads();
        const int tt = min(u.p2.cnt, 2048);
        for (int q = tt + tid; q < SORTN; q += 256) u.p2.dest[q] = 0ull;
        __syncthreads();
        // LDS bitonic over dest[0..2048), 256 threads x 4 pairs/step
        for (int k = 2; k <= SORTN; k <<= 1) {
            for (int j = k >> 1; j > 0; j >>= 1) {
                for (int p = tid; p < SORTN / 2; p += 256) {
                    int i = 2 * p - (p & (j - 1));
                    int l = i | j;
                    u64 a = u.p2.dest[i], c = u.p2.dest[l];
                    bool up = ((i & k) == 0);
                    bool sw = up ? (a < c) : (a > c);
                    if (sw) { u.p2.dest[i] = c; u.p2.dest[l] = a; }
                }
                __syncthreads();
            }
        }
        for (int r = tid; r < SORTN; r += 256)
            g_sorted[(size_t)b * SORTN + r] = u.p2.dest[r];
    }
}

// ===================== P3: decode + supmat + supT ==========================
__device__ void phase3(MegaLDS& u, int blk, int tid,
                       const float4* __restrict__ deltas,
                       const float4* __restrict__ anchors,
                       const u64* __restrict__ g_sorted,
                       float4* __restrict__ g_boxes,
                       uint32_t* __restrict__ g_supmat,
                       uint32_t* __restrict__ g_supT, int N)
{
    const int b = blk >> 3;
    const int s = blk & 7;

    const float4* dl = deltas + (size_t)b * N;
#pragma unroll
    for (int k = 0; k < 2; ++k) {
        int r = tid + k * 256;
        u.p3.box[r] = decode_key(g_sorted[(size_t)b * SORTN + r], dl,
                                 anchors, N);
    }
    __syncthreads();

    if (s == 0) {
#pragma unroll
        for (int k = 0; k < 2; ++k) {
            int r = tid + k * 256;
            g_boxes[(size_t)b * TILE + r] = u.p3.box[r];
        }
    }

    const int rbase = s * 64;
#pragma unroll
    for (int k = 0; k < 4; ++k) {
        int idx = tid + k * 256;             // [0, 1024)
        int row = rbase + (idx & 63);
        int w   = idx >> 6;                  // wave-uniform
        int jbase = w << 5;
        float4 bi = u.p3.box[row];
        float  ai = area_of(bi);
        uint32_t bits = 0u;
        if (jbase + 31 > row) {
#pragma unroll
            for (int c = 0; c < 32; ++c) {
                int j = jbase + c;
                float4 bj = u.p3.box[j];
                float  aj = area_of(bj);
                bool gt = (j > row) & iou_gt(bi, ai, bj, aj);  // branchless
                bits |= ((uint32_t)gt) << c;
            }
        }
        g_supmat[((size_t)b * TILE + row) * 16 + w] = bits;
    }

    // transposed diagonal block for chunk q = s (64 cols x 2 words)
    if (tid < 128) {
        int q  = s;
        int j  = tid >> 1;
        int w2 = tid & 1;
        int C  = q * 64 + j;
        float4 bc = u.p3.box[C];
        float  ac = area_of(bc);
        uint32_t bits = 0u;
#pragma unroll
        for (int c = 0; c < 32; ++c) {
            int R = q * 64 + w2 * 32 + c;
            float4 br = u.p3.box[R];
            float  ar = area_of(br);
            bool gt = (R < C) & iou_gt(br, ar, bc, ac);
            bits |= ((uint32_t)gt) << c;
        }
        g_supT[((size_t)b * TILE + C) * 2 + w2] = bits;
    }
}

// ===================== P4: greedy sweep (single wave) ======================
__device__ void phase4(MegaLDS& u, int b, int lane,
                       const uint32_t* __restrict__ g_supmat,
                       const u64* __restrict__ g_supT64,
                       const u64* __restrict__ g_sorted,
                       const float4* __restrict__ deltas,
                       const float4* __restrict__ anchors,
                       const float4* __restrict__ g_boxes,
                       float4* __restrict__ fb,        // global fallback boxes
                       float4* __restrict__ out, int N)
{
    const u64* tdbase = g_supT64 + (size_t)b * TILE;

    uint32_t removedw = 0u;                  // lanes 0..15: removed word
    int kc = 0, nq = 0;
    u64 cw_cur = tdbase[lane];
    for (int q = 0; q < TILE / 64; ++q) {
        u64 cw_next = (q < TILE / 64 - 1) ? tdbase[(q + 1) * 64 + lane] : 0ull;
        const int cbase = q << 6;
        uint32_t rlo = (uint32_t)__builtin_amdgcn_readlane((int)removedw, 2 * q);
        uint32_t rhi = (uint32_t)__builtin_amdgcn_readlane((int)removedw, 2 * q + 1);
        u64 avail = ~(((u64)rhi << 32) | rlo);
        u64 K = 0ull;
        while (avail) {                      // ballot-based greedy resolve
            int i = __ffsll((long long)avail) - 1;
            K |= (1ull << i);
            u64 supp = __ballot(((cw_cur >> i) & 1ull) != 0ull);
            avail &= ~(supp | (1ull << i));
        }
        if (lane == 0) u.p4.keepbits[q] = K;
        kc += __popcll(K);
        nq = q + 1;
        if (kc >= POST) break;
        if (K) {                             // masked pipelined propagation
            const int w = lane & 15;
            const int g = lane >> 4;
            const uint32_t* gs =
                g_supmat + ((size_t)b * TILE + cbase + g * 16) * 16 + w;
            uint32_t acc = 0u;
#pragma unroll
            for (int r = 0; r < 16; ++r) {
                uint32_t v = gs[(size_t)r * 16];
                uint32_t m = (uint32_t)0 - (uint32_t)((K >> (g * 16 + r)) & 1ull);
                acc |= (v & m);
            }
            acc |= (uint32_t)__shfl_xor((int)acc, 16, 64);
            acc |= (uint32_t)__shfl_xor((int)acc, 32, 64);
            if (lane < 16) removedw |= acc;
        }
        cw_cur = cw_next;
    }
    {
        int base = 0;
        for (int q = 0; q < nq; ++q) {
            u64 kbq = u.p4.keepbits[q];
            int pos = base + __popcll(kbq & ((1ull << lane) - 1));
            if (((kbq >> lane) & 1ull) && pos < POST)
                u.p4.kept[pos] = (uint32_t)(q * 64 + lane);
            base += __popcll(kbq);
        }
    }
    int kcf = min(kc, POST);                 // wave-uniform
    const bool fellback = (kcf < POST);

    if (fellback) {
        // exact continuation (never taken): boxes in global scratch fb
        const float4* dl = deltas + (size_t)b * N;
        for (int r = lane; r < PRE; r += 64)
            fb[r] = decode_key(g_sorted[(size_t)b * SORTN + r], dl, anchors, N);
        for (int w = lane; w < (PRE - TILE + 31) / 32; w += 64)
            u.p4.fmask[w] = 0u;
        for (int j = TILE + lane; j < PRE; j += 64) {
            float4 bj = fb[j];
            float  aj = area_of(bj);
            bool supd = false;
            for (int k = 0; k < kcf; ++k) {
                int i = (int)u.p4.kept[k];
                float4 bi = fb[i];
                if (iou_gt(bi, area_of(bi), bj, aj)) { supd = true; break; }
            }
            if (supd)
                atomicOr(&u.p4.fmask[(j - TILE) >> 5], 1u << ((j - TILE) & 31));
        }
        int i = TILE;
        while (i < PRE && kcf < POST) {
            while (i < PRE &&
                   ((u.p4.fmask[(i - TILE) >> 5] >> ((i - TILE) & 31)) & 1u)) ++i;
            if (i >= PRE) break;
            if (lane == 0) u.p4.kept[kcf] = (uint32_t)i;
            ++kcf;
            if (kcf >= POST) break;
            float4 bi = fb[i];
            float  ai = area_of(bi);
            for (int j = i + 1 + lane; j < PRE; j += 64) {
                float4 bj = fb[j];
                if (iou_gt(bi, ai, bj, area_of(bj)))
                    atomicOr(&u.p4.fmask[(j - TILE) >> 5],
                             1u << ((j - TILE) & 31));
            }
            ++i;
        }
    }

    float4* ob = out + (size_t)b * POST;
    for (int r = lane; r < POST; r += 64) {
        float4 o = make_float4(0.f, 0.f, 0.f, 0.f);
        if (r < kcf) {
            int ki = (int)u.p4.kept[r];
            float4 bx = fellback ? fb[ki] : g_boxes[(size_t)b * TILE + ki];
            o.x = fminf(fmaxf(bx.x, 0.f), 1.f);
            o.y = fminf(fmaxf(bx.y, 0.f), 1.f);
            o.z = fminf(fmaxf(bx.z, 0.f), 1.f);
            o.w = fminf(fmaxf(bx.w, 0.f), 1.f);
        }
        ob[r] = o;
    }
}

// ===================== cooperative mega-kernel =============================
__global__ __launch_bounds__(256, 2) void mega_kernel(
    const float4* __restrict__ score4,
    const float4* __restrict__ deltas,
    const float4* __restrict__ anchors,
    u64*      __restrict__ g_pairs,
    int*      __restrict__ g_scnt,
    uint32_t* __restrict__ g_shist,
    u64*      __restrict__ g_sorted,
    float4*   __restrict__ g_boxes,
    uint32_t* __restrict__ g_supmat,
    uint32_t* __restrict__ g_supT,
    float4*   __restrict__ fb_scratch,   // [B*PRE] aliases g_pairs region
    float4*   __restrict__ out,
    int N, int B)
{
    cg::grid_group grid = cg::this_grid();
    const int blk = blockIdx.x;
    const int tid = threadIdx.x;
    __shared__ MegaLDS u;

    phase1(u, blk, tid, score4, g_pairs, g_scnt, g_shist, N);
    grid.sync();
    if (blk < B)
        phase2(u, blk, tid, score4, g_pairs, g_scnt, g_shist, g_sorted, N);
    grid.sync();
    phase3(u, blk, tid, deltas, anchors, g_sorted, g_boxes, g_supmat,
           g_supT, N);
    grid.sync();
    if (blk < B && tid < 64)
        phase4(u, blk, tid, g_supmat, (const u64*)g_supT, g_sorted, deltas,
               anchors, g_boxes, fb_scratch + (size_t)blk * PRE, out, N);
}

// ===================== standalone pipeline kernels =========================
__global__ __launch_bounds__(256) void k_p1(
    const float4* __restrict__ score4, u64* __restrict__ g_pairs,
    int* __restrict__ g_scnt, uint32_t* __restrict__ g_shist, int N)
{
    __shared__ MegaLDS u;
    phase1(u, blockIdx.x, threadIdx.x, score4, g_pairs, g_scnt, g_shist, N);
}

__global__ __launch_bounds__(256) void k_p2(
    const float4* __restrict__ score4, const u64* __restrict__ g_pairs,
    const int* __restrict__ g_scnt, const uint32_t* __restrict__ g_shist,
    u64* __restrict__ g_sorted, int N)
{
    __shared__ MegaLDS u;
    phase2(u, blockIdx.x, threadIdx.x, score4, g_pairs, g_scnt, g_shist,
           g_sorted, N);
}

__global__ __launch_bounds__(256) void k_p3(
    const float4* __restrict__ deltas, const float4* __restrict__ anchors,
    const u64* __restrict__ g_sorted, float4* __restrict__ g_boxes,
    uint32_t* __restrict__ g_supmat, uint32_t* __restrict__ g_supT, int N)
{
    __shared__ MegaLDS u;
    phase3(u, blockIdx.x, threadIdx.x, deltas, anchors, g_sorted, g_boxes,
           g_supmat, g_supT, N);
}

__global__ __launch_bounds__(64) void k_p4(
    const uint32_t* __restrict__ g_supmat, const u64* __restrict__ g_supT64,
    const u64* __restrict__ g_sorted, const float4* __restrict__ deltas,
    const float4* __restrict__ anchors, const float4* __restrict__ g_boxes,
    float4* __restrict__ fb_scratch, float4* __restrict__ out, int N)
{
    __shared__ MegaLDS u;
    phase4(u, blockIdx.x, threadIdx.x, g_supmat, g_supT64, g_sorted, deltas,
           anchors, g_boxes, fb_scratch + (size_t)blockIdx.x * PRE, out, N);
}

extern "C" void kernel_launch(void* const* d_in, const int* in_sizes, int n_in,
                              void* d_out, int out_size, void* d_ws, size_t ws_size,
                              hipStream_t stream) {
    const float4* deltas  = (const float4*)d_in[0];
    const float*  labels  = (const float*)d_in[1];
    const float4* anchors = (const float4*)d_in[2];
    const float4* score4  = (const float4*)labels;
    float4*       outp    = (float4*)d_out;
    int N = in_sizes[2] / 4;            // 90000
    int B = in_sizes[1] / N;            // 64

    // workspace (16B-aligned chunks), no zero-init required anywhere:
    // boxes | pairs | sorted | supmat | supT | shist | scnt
    char* ws = (char*)d_ws;
    const size_t SZ_BOXES  = (size_t)B * TILE * 16;
    const size_t SZ_PAIRS  = (size_t)B * SL * KBUF * 8;   // >= B*PRE*16
    const size_t SZ_SORTED = (size_t)B * SORTN * 8;
    const size_t SZ_SUPMAT = (size_t)B * TILE * 16 * 4;
    const size_t SZ_SUPT   = (size_t)B * TILE * 8;
    const size_t SZ_SHIST  = (size_t)B * SL * 64 * 4;
    float4*   g_boxes  = (float4*)ws;
    u64*      g_pairs  = (u64*)(ws + SZ_BOXES);
    u64*      g_sorted = (u64*)(ws + SZ_BOXES + SZ_PAIRS);
    uint32_t* g_supmat = (uint32_t*)(ws + SZ_BOXES + SZ_PAIRS + SZ_SORTED);
    uint32_t* g_supT   = (uint32_t*)(ws + SZ_BOXES + SZ_PAIRS + SZ_SORTED + SZ_SUPMAT);
    uint32_t* g_shist  = (uint32_t*)(ws + SZ_BOXES + SZ_PAIRS + SZ_SORTED + SZ_SUPMAT + SZ_SUPT);
    int*      g_scnt   = (int*)((char*)g_shist + SZ_SHIST);
    float4*   fb       = (float4*)g_pairs;   // fallback scratch (dead by P4)

    // capture-safe host-side gate: does the runtime allow 512 co-resident?
    int dev = 0, numCU = 0, maxB = 0;
    hipGetDevice(&dev);
    hipDeviceGetAttribute(&numCU, hipDeviceAttributeMultiprocessorCount, dev);
    hipOccupancyMaxActiveBlocksPerMultiprocessor(&maxB, (const void*)mega_kernel,
                                                 256, 0);
    const int grid = B * SL;            // 512
    if ((long long)maxB * numCU >= grid) {
        void* args[] = {
            (void*)&score4, (void*)&deltas, (void*)&anchors,
            (void*)&g_pairs, (void*)&g_scnt, (void*)&g_shist,
            (void*)&g_sorted, (void*)&g_boxes, (void*)&g_supmat,
            (void*)&g_supT, (void*)&fb, (void*)&outp, (void*)&N, (void*)&B
        };
        hipError_t e = hipLaunchCooperativeKernel((void*)mega_kernel,
                                                  dim3(grid), dim3(256),
                                                  args, 0, stream);
        if (e == hipSuccess) return;
    }
    // pipeline fallback (identical phase logic)
    k_p1<<<B * SL, 256, 0, stream>>>(score4, g_pairs, g_scnt, g_shist, N);
    k_p2<<<B, 256, 0, stream>>>(score4, g_pairs, g_scnt, g_shist, g_sorted, N);
    k_p3<<<B * SL, 256, 0, stream>>>(deltas, anchors, g_sorted, g_boxes,
                                     g_supmat, g_supT, N);
    k_p4<<<B, 64, 0, stream>>>(g_supmat, (const u64*)g_supT, g_sorted,
                               deltas, anchors, g_boxes, fb, outp, N);
}